// Round 6
// baseline (749.364 us; speedup 1.0000x reference)
//
#include <hip/hip_runtime.h>
#include <stdint.h>

// AttentionModule: S=512, B=64, H=1024. Inputs f32, OUTPUT f32 (r5 bisect:
// three numerically-independent pipelines agreed bit-identically -> checker
// reads f32; bf16-packed writes were the sole bug).
// MFMA pipeline (cross-validated against pure-f32 r5):
//   U[b,j]     = hidden[b,:] @ W_attn[j,:1024].T + b_attn[j]          (mode-0 GEMM)
//   scores[s*64+b] += sum_j tanh(Enc@W_attn[:,1024:].T + U) * W_attn2 (mode-1 GEMM, fused)
//   (b_attn2 dropped: uniform shift into softmax)
//   attnw = softmax_s(scores) ; applied[b,h] = sum_s attnw*enc (f32)
//   out = tanh(cat(dec, applied) @ W_comb.T + b_comb)                 (mode-2 GEMM)

typedef __attribute__((ext_vector_type(8))) short bf16x8;
typedef __attribute__((ext_vector_type(4))) float f32x4;

__device__ __forceinline__ uint16_t f2bf(float x) {
  uint32_t u = __float_as_uint(x);
  u += 0x7fffu + ((u >> 16) & 1u);   // RNE
  return (uint16_t)(u >> 16);
}
__device__ __forceinline__ uint32_t pk2(float a, float b) {
  return (uint32_t)f2bf(a) | ((uint32_t)f2bf(b) << 16);
}
// load 8 f32, convert to 8 bf16 packed in a uint4 (16B)
__device__ __forceinline__ uint4 ldcvt8(const float* __restrict__ p) {
  const float4 a = *(const float4*)p;
  const float4 b = *(const float4*)(p + 4);
  uint4 r;
  r.x = pk2(a.x, a.y);
  r.y = pk2(a.z, a.w);
  r.z = pk2(b.x, b.y);
  r.w = pk2(b.z, b.w);
  return r;
}

// ---- 128x128-tile GEMM. A:[M,K] row-major (f32 if AF32 else bf16, lda elems);
// B:[N,K] row-major f32 (ldb elems) = B^T input. Biases f32.
// MODE 0: outf[gm*2048+gn] = acc + bias[gn]
// MODE 1: atomicAdd(outf[gm], sum_n tanh(acc + U[gm&63, gn]) * bias[gn])
// MODE 2: outf[gm*1024+gn] = tanh(acc + bias[gn])            (f32 store)
template <int MODE, bool AF32>
__global__ __launch_bounds__(256)
void gemm_kernel(const void* __restrict__ Av, int lda,
                 const float* __restrict__ B32, int ldb,
                 int M, int K,
                 float* __restrict__ outf,
                 const float* __restrict__ Ubias,
                 const float* __restrict__ bias) {
  __shared__ __align__(16) uint16_t sA[128 * 32];
  __shared__ __align__(16) uint16_t sB[128 * 32];

  const int t = threadIdx.x;
  const int lane = t & 63;
  const int wave = t >> 6;
  const int wm = wave >> 1;      // 2x2 waves over 128x128 -> 64x64 per wave
  const int wn = wave & 1;

  const int bn0 = blockIdx.x * 128;
  const int bm0 = blockIdx.y * 128;

  // staging map: thread t covers tile row t>>2, k-chunk (t&3)*8
  const int srow = t >> 2;
  const int scol = (t & 3) * 8;
  const int ar0 = min(bm0 + srow, M - 1);        // clamp (M=64 modes)
  const int ar1 = min(bm0 + 64 + srow, M - 1);
  const float*    a32 = (const float*)Av;
  const uint16_t* a16 = (const uint16_t*)Av;
  const float* bp0 = B32 + (size_t)(bn0 + srow) * ldb + scol;
  const float* bp1 = B32 + (size_t)(bn0 + 64 + srow) * ldb + scol;

  f32x4 acc[4][4];
#pragma unroll
  for (int i = 0; i < 4; ++i)
#pragma unroll
    for (int j = 0; j < 4; ++j) acc[i][j] = (f32x4){0.f, 0.f, 0.f, 0.f};

  // fragment maps (m97-verified, cross-validated vs r5 f32 pipeline)
  const int mrow = wm * 64 + (lane & 15);
  const int nrow = wn * 64 + (lane & 15);
  const int kq = (lane >> 4) * 8;

  const int nsteps = K >> 5;
  for (int kk = 0; kk < nsteps; ++kk) {
    const int k0 = kk << 5;
    uint4 va0, va1;
    if (AF32) {
      va0 = ldcvt8(a32 + (size_t)ar0 * lda + scol + k0);
      va1 = ldcvt8(a32 + (size_t)ar1 * lda + scol + k0);
    } else {
      va0 = *(const uint4*)(a16 + (size_t)ar0 * lda + scol + k0);
      va1 = *(const uint4*)(a16 + (size_t)ar1 * lda + scol + k0);
    }
    const uint4 vb0 = ldcvt8(bp0 + k0);
    const uint4 vb1 = ldcvt8(bp1 + k0);
    __syncthreads();   // previous iteration's LDS reads complete
    *(uint4*)&sA[t * 8] = va0;          // rows 0..63
    *(uint4*)&sA[2048 + t * 8] = va1;   // rows 64..127
    *(uint4*)&sB[t * 8] = vb0;
    *(uint4*)&sB[2048 + t * 8] = vb1;
    __syncthreads();   // stores visible

    bf16x8 af[4], bfr[4];
#pragma unroll
    for (int i = 0; i < 4; ++i)
      af[i] = *(const bf16x8*)&sA[(mrow + i * 16) * 32 + kq];
#pragma unroll
    for (int j = 0; j < 4; ++j)
      bfr[j] = *(const bf16x8*)&sB[(nrow + j * 16) * 32 + kq];

#pragma unroll
    for (int i = 0; i < 4; ++i)
#pragma unroll
      for (int j = 0; j < 4; ++j)
        acc[i][j] = __builtin_amdgcn_mfma_f32_16x16x32_bf16(af[i], bfr[j], acc[i][j], 0, 0, 0);
  }

  // C/D layout: col = lane&15, row = (lane>>4)*4 + reg   [m89/m91 verified]
  const int colb = lane & 15;
  const int rquad = lane >> 4;
  if (MODE == 1) {
    float w2f[4];
#pragma unroll
    for (int j = 0; j < 4; ++j) w2f[j] = bias[bn0 + wn * 64 + j * 16 + colb];
#pragma unroll
    for (int i = 0; i < 4; ++i) {
#pragma unroll
      for (int r = 0; r < 4; ++r) {
        const int gm = bm0 + wm * 64 + i * 16 + rquad * 4 + r;  // = s*64 + b
        const int bb = gm & 63;
        float p = 0.f;
#pragma unroll
        for (int j = 0; j < 4; ++j) {
          const int gn = bn0 + wn * 64 + j * 16 + colb;
          p += tanhf(acc[i][j][r] + Ubias[bb * 2048 + gn]) * w2f[j];
        }
        p += __shfl_xor(p, 1);
        p += __shfl_xor(p, 2);
        p += __shfl_xor(p, 4);
        p += __shfl_xor(p, 8);
        if (colb == 0) atomicAdd(outf + gm, p);
      }
    }
  } else {
#pragma unroll
    for (int i = 0; i < 4; ++i) {
#pragma unroll
      for (int r = 0; r < 4; ++r) {
        const int gm = bm0 + wm * 64 + i * 16 + rquad * 4 + r;
        if (gm < M) {
#pragma unroll
          for (int j = 0; j < 4; ++j) {
            const int gn = bn0 + wn * 64 + j * 16 + colb;
            const float v = acc[i][j][r] + bias[gn];
            if (MODE == 0)
              outf[gm * 2048 + gn] = v;
            else
              outf[gm * 1024 + gn] = tanhf(v);   // f32 store
          }
        }
      }
    }
  }
}

// softmax over s (512) per b; scores layout [s*64+b]
__global__ void softmax_kernel(const float* __restrict__ scores, float* __restrict__ attnw) {
  const int b = blockIdx.x;
  const int lane = threadIdx.x;
  float v[8];
  float mx = -1e30f;
#pragma unroll
  for (int i = 0; i < 8; ++i) {
    v[i] = scores[(size_t)(lane + i * 64) * 64 + b];
    mx = fmaxf(mx, v[i]);
  }
#pragma unroll
  for (int off = 32; off >= 1; off >>= 1) mx = fmaxf(mx, __shfl_xor(mx, off));
  float sum = 0.f;
#pragma unroll
  for (int i = 0; i < 8; ++i) {
    v[i] = __expf(v[i] - mx);
    sum += v[i];
  }
#pragma unroll
  for (int off = 32; off >= 1; off >>= 1) sum += __shfl_xor(sum, off);
  const float inv = 1.f / sum;
#pragma unroll
  for (int i = 0; i < 8; ++i) attnw[b * 512 + lane + i * 64] = v[i] * inv;
}

// applied[b,h] = sum_s attnw[b,s]*enc[s,b,h] (f32). Writes f32 output-1 and
// bf16 A_cat = [dec | applied] for the final MFMA GEMM.
__global__ __launch_bounds__(256)
void applied_kernel(const float* __restrict__ enc, const float* __restrict__ dec,
                    const float* __restrict__ attnw,
                    float* __restrict__ out_applied, uint16_t* __restrict__ acat) {
  const int b = blockIdx.x;
  const int half = blockIdx.y;
  const int t = threadIdx.x;
  __shared__ float w[512];
  w[t] = attnw[b * 512 + t];
  w[t + 256] = attnw[b * 512 + 256 + t];
  __syncthreads();
  const int h = half * 512 + t * 2;
  const float2* base = (const float2*)(enc + (size_t)b * 1024 + h);
  float a0 = 0.f, a1 = 0.f;
#pragma unroll 4
  for (int s = 0; s < 512; ++s) {
    const float2 p = base[(size_t)s * 32768];   // s stride = B*H floats = 32768 float2
    a0 += w[s] * p.x;
    a1 += w[s] * p.y;
  }
  *(float2*)(out_applied + (size_t)b * 1024 + h) = make_float2(a0, a1);
  *(uint32_t*)(acat + (size_t)b * 2048 + 1024 + h) = pk2(a0, a1);
  *(uint32_t*)(acat + (size_t)b * 2048 + h) =
      pk2(dec[(size_t)b * 1024 + h], dec[(size_t)b * 1024 + h + 1]);
}

extern "C" void kernel_launch(void* const* d_in, const int* in_sizes, int n_in,
                              void* d_out, int out_size, void* d_ws, size_t ws_size,
                              hipStream_t stream) {
  const float* hidden  = (const float*)d_in[0];   // [64,1024]
  const float* dec     = (const float*)d_in[1];   // [64,1024]
  const float* enc     = (const float*)d_in[2];   // [512,64,1024]
  const float* W_attn  = (const float*)d_in[3];   // [2048,2048]
  const float* b_attn  = (const float*)d_in[4];   // [2048]
  const float* W_attn2 = (const float*)d_in[5];   // [1,2048]
  // d_in[6] = b_attn2: uniform shift into softmax -> dropped
  const float* W_comb  = (const float*)d_in[7];   // [1024,2048]
  const float* b_comb  = (const float*)d_in[8];   // [1024]
  float* outp = (float*)d_out;                    // [out 65536 | applied 65536] f32

  char* ws = (char*)d_ws;                      // 1 MB total
  float* scores = (float*)(ws + 0);            // 32768 f32
  float* U      = (float*)(ws + 131072);       // 131072 f32
  float* attnw  = (float*)(ws + 655360);       // 32768 f32
  uint16_t* acat = (uint16_t*)(ws + 786432);   // 131072 bf16 -> ends at 1048576

  hipMemsetAsync(scores, 0, 131072, stream);

  // U = hidden @ W_attn[:, :1024].T + b_attn
  gemm_kernel<0, true><<<dim3(16, 1), 256, 0, stream>>>(
      hidden, 1024, W_attn, 2048, 64, 1024, U, nullptr, b_attn);
  // scores += sum_j tanh(enc @ W_attn[:, 1024:].T + U) * W_attn2
  gemm_kernel<1, true><<<dim3(16, 256), 256, 0, stream>>>(
      enc, 1024, W_attn + 1024, 2048, 32768, 1024, scores, U, W_attn2);
  softmax_kernel<<<64, 64, 0, stream>>>(scores, attnw);
  applied_kernel<<<dim3(64, 2), 256, 0, stream>>>(enc, dec, attnw, outp + 65536, acat);
  // out = tanh(A_cat @ W_comb.T + b_comb)
  gemm_kernel<2, false><<<dim3(8, 1), 256, 0, stream>>>(
      acat, 2048, W_comb, 2048, 64, 2048, outp, nullptr, b_comb);
}

// Round 7
// 556.469 us; speedup vs baseline: 1.3466x; 1.3466x over previous
//
#include <hip/hip_runtime.h>
#include <stdint.h>

// AttentionModule: S=512, B=64, H=1024. Inputs f32, output f32 (validated r6).
// R7: kill the staging-conversion VALU bottleneck (r6: VALUBusy 56% / MfmaUtil 14%).
//   - one-shot f32->bf16 convert of enc / W_attn[:,1024:] / W_comb into ws
//   - mode-1/2 GEMMs use m97-style global_load_lds width-16 staging (bf16 in HBM)
//   - epilogue: U tile in LDS + fast tanh
// Pipeline:
//   U = hidden @ W_attn[:, :1024].T + b_attn                      (mode-0, f32 inline staging)
//   scores[s*64+b] += sum_j tanh(enc@Wa_r.T + U)*W_attn2          (mode-1 bf16 GEMM, fused)
//   attnw = softmax_s(scores); applied = sum_s attnw*enc
//   out = tanh(cat(dec,applied) @ W_comb.T + b_comb)              (mode-2 bf16 GEMM)

typedef __attribute__((ext_vector_type(8))) short bf16x8;
typedef __attribute__((ext_vector_type(4))) float f32x4;

__device__ __forceinline__ float bf2f(uint16_t u) {
  return __uint_as_float(((uint32_t)u) << 16);
}
__device__ __forceinline__ uint16_t f2bf(float x) {
  uint32_t u = __float_as_uint(x);
  u += 0x7fffu + ((u >> 16) & 1u);   // RNE
  return (uint16_t)(u >> 16);
}
__device__ __forceinline__ uint32_t pk2(float a, float b) {
  return (uint32_t)f2bf(a) | ((uint32_t)f2bf(b) << 16);
}
__device__ __forceinline__ uint4 cvt8(const float* __restrict__ p) {
  const float4 a = *(const float4*)p;
  const float4 b = *(const float4*)(p + 4);
  uint4 r;
  r.x = pk2(a.x, a.y); r.y = pk2(a.z, a.w);
  r.z = pk2(b.x, b.y); r.w = pk2(b.z, b.w);
  return r;
}
// tanh(x) = 1 - 2/(exp(2x)+1); |err| ~1e-6, saturates correctly at +-inf
__device__ __forceinline__ float tanh_fast(float x) {
  const float e = __expf(2.f * x);
  return __builtin_fmaf(-2.f, __builtin_amdgcn_rcpf(e + 1.f), 1.f);
}
// async global->LDS, 16B/lane; LDS dest is wave-uniform base + lane*16
__device__ __forceinline__ void load16(const uint16_t* g, uint16_t* l) {
  __builtin_amdgcn_global_load_lds(
      (const __attribute__((address_space(1))) void*)g,
      (__attribute__((address_space(3))) void*)l, 16, 0, 0);
}

// flat f32 -> bf16, 8 elems/thread
__global__ __launch_bounds__(256)
void cvt_kernel(const float* __restrict__ src, uint16_t* __restrict__ dst, int n8) {
  const int i = blockIdx.x * 256 + threadIdx.x;
  if (i < n8) ((uint4*)dst)[i] = cvt8(src + (size_t)i * 8);
}
// W_attn[:,1024:2048] -> compact [2048,1024] bf16
__global__ __launch_bounds__(256)
void cvt_wa_kernel(const float* __restrict__ W, uint16_t* __restrict__ dst) {
  const int i = blockIdx.x * 256 + threadIdx.x;   // i in [0, 2048*128)
  const int j = i >> 7, c8 = i & 127;
  ((uint4*)dst)[j * 128 + c8] = cvt8(W + (size_t)j * 2048 + 1024 + c8 * 8);
}

// ---- mode-0: U = hidden @ W_attn[:, :1024].T + b_attn  (f32 inputs, r6-proven)
__global__ __launch_bounds__(256)
void gemm_u_kernel(const float* __restrict__ A, const float* __restrict__ B32,
                   float* __restrict__ outf, const float* __restrict__ bias) {
  __shared__ __align__(16) uint16_t sA[128 * 32];
  __shared__ __align__(16) uint16_t sB[128 * 32];
  const int t = threadIdx.x, lane = t & 63, wave = t >> 6;
  const int wm = wave >> 1, wn = wave & 1;
  const int bn0 = blockIdx.x * 128;
  const int srow = t >> 2, scol = (t & 3) * 8;
  const int ar0 = min(srow, 63), ar1 = min(64 + srow, 63);
  f32x4 acc[4][4];
#pragma unroll
  for (int i = 0; i < 4; ++i)
#pragma unroll
    for (int j = 0; j < 4; ++j) acc[i][j] = (f32x4){0.f, 0.f, 0.f, 0.f};
  const int mrow = wm * 64 + (lane & 15);
  const int nrow = wn * 64 + (lane & 15);
  const int kq = (lane >> 4) * 8;
  for (int kk = 0; kk < 32; ++kk) {
    const int k0 = kk << 5;
    const uint4 va0 = cvt8(A + (size_t)ar0 * 1024 + scol + k0);
    const uint4 va1 = cvt8(A + (size_t)ar1 * 1024 + scol + k0);
    const uint4 vb0 = cvt8(B32 + (size_t)(bn0 + srow) * 2048 + scol + k0);
    const uint4 vb1 = cvt8(B32 + (size_t)(bn0 + 64 + srow) * 2048 + scol + k0);
    __syncthreads();
    *(uint4*)&sA[t * 8] = va0;
    *(uint4*)&sA[2048 + t * 8] = va1;
    *(uint4*)&sB[t * 8] = vb0;
    *(uint4*)&sB[2048 + t * 8] = vb1;
    __syncthreads();
    bf16x8 af[4], bfr[4];
#pragma unroll
    for (int i = 0; i < 4; ++i) af[i] = *(const bf16x8*)&sA[(mrow + i * 16) * 32 + kq];
#pragma unroll
    for (int j = 0; j < 4; ++j) bfr[j] = *(const bf16x8*)&sB[(nrow + j * 16) * 32 + kq];
#pragma unroll
    for (int i = 0; i < 4; ++i)
#pragma unroll
      for (int j = 0; j < 4; ++j)
        acc[i][j] = __builtin_amdgcn_mfma_f32_16x16x32_bf16(af[i], bfr[j], acc[i][j], 0, 0, 0);
  }
  const int colb = lane & 15, rquad = lane >> 4;
#pragma unroll
  for (int i = 0; i < 4; ++i)
#pragma unroll
    for (int r = 0; r < 4; ++r) {
      const int gm = wm * 64 + i * 16 + rquad * 4 + r;
      if (gm < 64) {
#pragma unroll
        for (int j = 0; j < 4; ++j) {
          const int gn = bn0 + wn * 64 + j * 16 + colb;
          outf[gm * 2048 + gn] = acc[i][j][r] + bias[gn];
        }
      }
    }
}

// ---- bf16 GEMM, global_load_lds staging (m97 structure).
// A:[M,K] bf16 (lda), B:[N,K] bf16 (ldb).
// MODE 1: atomicAdd(scores[gm], sum_n tanh(acc + U[gm&63,gn]) * w2[gn])
// MODE 2: outf[gm*1024+gn] = tanh(acc + bias[gn])
template <int MODE>
__global__ __launch_bounds__(256)
void gemm_bf_kernel(const uint16_t* __restrict__ A, int lda,
                    const uint16_t* __restrict__ Bm, int ldb,
                    int M, int K,
                    float* __restrict__ outf,
                    const float* __restrict__ Ubias,
                    const float* __restrict__ bias) {
  __shared__ __align__(16) uint16_t sAB[2][128 * 32];  // 32 KB; reused as U-tile
  uint16_t* sA = sAB[0];
  uint16_t* sB = sAB[1];
  float* sU = (float*)sAB;

  const int t = threadIdx.x, lane = t & 63, wave = t >> 6;
  const int wm = wave >> 1, wn = wave & 1;
  const int bn0 = blockIdx.x * 128;
  const int bm0 = blockIdx.y * 128;

  const int srow = t >> 2, scol = (t & 3) * 8;
  const int ar0 = min(bm0 + srow, M - 1);
  const int ar1 = min(bm0 + 64 + srow, M - 1);
  const uint16_t* agp0 = A + (size_t)ar0 * lda + scol;
  const uint16_t* agp1 = A + (size_t)ar1 * lda + scol;
  const uint16_t* bgp0 = Bm + (size_t)(bn0 + srow) * ldb + scol;
  const uint16_t* bgp1 = Bm + (size_t)(bn0 + 64 + srow) * ldb + scol;

  // wave-uniform LDS bases: lane l lands at base + l*16B (rows wave*16 + l/4)
  uint16_t* la0 = sA + wave * 512;
  uint16_t* la1 = sA + 2048 + wave * 512;
  uint16_t* lb0 = sB + wave * 512;
  uint16_t* lb1 = sB + 2048 + wave * 512;

  f32x4 acc[4][4];
#pragma unroll
  for (int i = 0; i < 4; ++i)
#pragma unroll
    for (int j = 0; j < 4; ++j) acc[i][j] = (f32x4){0.f, 0.f, 0.f, 0.f};

  const int mrow = wm * 64 + (lane & 15);
  const int nrow = wn * 64 + (lane & 15);
  const int kq = (lane >> 4) * 8;

  const int nsteps = K >> 5;
  for (int kk = 0; kk < nsteps; ++kk) {
    const int k0 = kk << 5;
    load16(agp0 + k0, la0);
    load16(agp1 + k0, la1);
    load16(bgp0 + k0, lb0);
    load16(bgp1 + k0, lb1);
    __syncthreads();   // drains vmcnt -> LDS writes visible

    bf16x8 af[4], bfr[4];
#pragma unroll
    for (int i = 0; i < 4; ++i) af[i] = *(const bf16x8*)&sA[(mrow + i * 16) * 32 + kq];
#pragma unroll
    for (int j = 0; j < 4; ++j) bfr[j] = *(const bf16x8*)&sB[(nrow + j * 16) * 32 + kq];
#pragma unroll
    for (int i = 0; i < 4; ++i)
#pragma unroll
      for (int j = 0; j < 4; ++j)
        acc[i][j] = __builtin_amdgcn_mfma_f32_16x16x32_bf16(af[i], bfr[j], acc[i][j], 0, 0, 0);
    __syncthreads();   // fragment reads done before next-iter overwrite
  }

  const int colb = lane & 15, rquad = lane >> 4;
  if (MODE == 1) {
    // stage U[0:64, bn0:bn0+128] into LDS (f32, 32 KB)
#pragma unroll
    for (int q = 0; q < 8; ++q) {
      const int idx = t + q * 256;           // [0,2048) float4s
      const int b = idx >> 5, c4 = idx & 31;
      ((float4*)sU)[idx] = *(const float4*)&Ubias[b * 2048 + bn0 + c4 * 4];
    }
    __syncthreads();
    float w2f[4];
#pragma unroll
    for (int j = 0; j < 4; ++j) w2f[j] = bias[bn0 + wn * 64 + j * 16 + colb];
#pragma unroll
    for (int i = 0; i < 4; ++i) {
#pragma unroll
      for (int r = 0; r < 4; ++r) {
        const int gm = bm0 + wm * 64 + i * 16 + rquad * 4 + r;  // = s*64 + b
        const int bb = gm & 63;
        float p = 0.f;
#pragma unroll
        for (int j = 0; j < 4; ++j) {
          const float u = sU[bb * 128 + wn * 64 + j * 16 + colb];
          p += tanh_fast(acc[i][j][r] + u) * w2f[j];
        }
        p += __shfl_xor(p, 1);
        p += __shfl_xor(p, 2);
        p += __shfl_xor(p, 4);
        p += __shfl_xor(p, 8);
        if (colb == 0) atomicAdd(outf + gm, p);
      }
    }
  } else {
#pragma unroll
    for (int i = 0; i < 4; ++i)
#pragma unroll
      for (int r = 0; r < 4; ++r) {
        const int gm = bm0 + wm * 64 + i * 16 + rquad * 4 + r;
        if (gm < M) {
#pragma unroll
          for (int j = 0; j < 4; ++j) {
            const int gn = bn0 + wn * 64 + j * 16 + colb;
            outf[gm * 1024 + gn] = tanh_fast(acc[i][j][r] + bias[gn]);
          }
        }
      }
  }
}

// softmax over s (512) per b; scores layout [s*64+b]
__global__ void softmax_kernel(const float* __restrict__ scores, float* __restrict__ attnw) {
  const int b = blockIdx.x, lane = threadIdx.x;
  float v[8];
  float mx = -1e30f;
#pragma unroll
  for (int i = 0; i < 8; ++i) {
    v[i] = scores[(size_t)(lane + i * 64) * 64 + b];
    mx = fmaxf(mx, v[i]);
  }
#pragma unroll
  for (int off = 32; off >= 1; off >>= 1) mx = fmaxf(mx, __shfl_xor(mx, off));
  float sum = 0.f;
#pragma unroll
  for (int i = 0; i < 8; ++i) {
    v[i] = __expf(v[i] - mx);
    sum += v[i];
  }
#pragma unroll
  for (int off = 32; off >= 1; off >>= 1) sum += __shfl_xor(sum, off);
  const float inv = 1.f / sum;
#pragma unroll
  for (int i = 0; i < 8; ++i) attnw[b * 512 + lane + i * 64] = v[i] * inv;
}

// applied[b,h] = sum_s attnw[b,s]*enc_bf[s,b,h]; f32 out + bf16 A_cat row
__global__ __launch_bounds__(256)
void applied_kernel(const uint16_t* __restrict__ encb, const float* __restrict__ dec,
                    const float* __restrict__ attnw,
                    float* __restrict__ out_applied, uint16_t* __restrict__ acat) {
  const int b = blockIdx.x, half = blockIdx.y, t = threadIdx.x;
  __shared__ float w[512];
  w[t] = attnw[b * 512 + t];
  w[t + 256] = attnw[b * 512 + 256 + t];
  __syncthreads();
  const int h = half * 512 + t * 2;
  const uint32_t* base = (const uint32_t*)encb + (size_t)b * 512 + (h >> 1);
  float a0 = 0.f, a1 = 0.f;
#pragma unroll 8
  for (int s = 0; s < 512; ++s) {
    const uint32_t p = base[(size_t)s * 32768];   // s stride = B*H/2 uint32
    a0 += w[s] * bf2f((uint16_t)(p & 0xffffu));
    a1 += w[s] * bf2f((uint16_t)(p >> 16));
  }
  *(float2*)(out_applied + (size_t)b * 1024 + h) = make_float2(a0, a1);
  *(uint32_t*)(acat + (size_t)b * 2048 + 1024 + h) = pk2(a0, a1);
  *(uint32_t*)(acat + (size_t)b * 2048 + h) =
      pk2(dec[(size_t)b * 1024 + h], dec[(size_t)b * 1024 + h + 1]);
}

extern "C" void kernel_launch(void* const* d_in, const int* in_sizes, int n_in,
                              void* d_out, int out_size, void* d_ws, size_t ws_size,
                              hipStream_t stream) {
  const float* hidden  = (const float*)d_in[0];
  const float* dec     = (const float*)d_in[1];
  const float* enc     = (const float*)d_in[2];
  const float* W_attn  = (const float*)d_in[3];
  const float* b_attn  = (const float*)d_in[4];
  const float* W_attn2 = (const float*)d_in[5];
  const float* W_comb  = (const float*)d_in[7];
  const float* b_comb  = (const float*)d_in[8];
  float* outp = (float*)d_out;                 // [out 65536 | applied 65536] f32

  char* ws = (char*)d_ws;
  float*    scores = (float*)(ws + 0);             // 128 KB
  float*    U      = (float*)(ws + 131072);        // 512 KB
  float*    attnw  = (float*)(ws + 655360);        // 128 KB
  uint16_t* acat   = (uint16_t*)(ws + 786432);     // 256 KB
  uint16_t* enc_bf = (uint16_t*)(ws + 1048576);    // 64 MB
  uint16_t* Wa_bf  = (uint16_t*)(ws + 68157440);   // 4 MB  [2048,1024]
  uint16_t* Wc_bf  = (uint16_t*)(ws + 72351744);   // 4 MB  [1024,2048] -> ends ~73 MB

  hipMemsetAsync(scores, 0, 131072, stream);

  cvt_kernel<<<16384, 256, 0, stream>>>(enc, enc_bf, 33554432 / 8);
  cvt_wa_kernel<<<1024, 256, 0, stream>>>(W_attn, Wa_bf);
  cvt_kernel<<<1024, 256, 0, stream>>>(W_comb, Wc_bf, 2097152 / 8);

  // U = hidden @ W_attn[:, :1024].T + b_attn
  gemm_u_kernel<<<16, 256, 0, stream>>>(hidden, W_attn, U, b_attn);
  // scores += sum_j tanh(enc @ Wa_r.T + U) * W_attn2
  gemm_bf_kernel<1><<<dim3(16, 256), 256, 0, stream>>>(
      enc_bf, 1024, Wa_bf, 1024, 32768, 1024, scores, U, W_attn2);
  softmax_kernel<<<64, 64, 0, stream>>>(scores, attnw);
  applied_kernel<<<dim3(64, 2), 256, 0, stream>>>(enc_bf, dec, attnw, outp + 65536, acat);
  // out = tanh(A_cat @ W_comb.T + b_comb)
  gemm_bf_kernel<2><<<dim3(8, 1), 256, 0, stream>>>(
      acat, 2048, Wc_bf, 2048, 64, 2048, outp, nullptr, b_comb);
}

// Round 8
// 523.037 us; speedup vs baseline: 1.4327x; 1.0639x over previous
//
#include <hip/hip_runtime.h>
#include <stdint.h>

// AttentionModule: S=512, B=64, H=1024. Inputs f32, output f32.
// R8: launch-count 9->6, split-K U-GEMM, mode-1 grid swap for L2 locality.
//   init: scores=0, U=b_attn broadcast
//   cvt_all: enc/Wa_right/Wc -> bf16 (one launch)
//   gemm_u: split-K(4) atomicAdd into U
//   mode-1: scores += sum_j tanh(enc@Wa_r.T + U)*W_attn2   (m-fast grid)
//   applied: fused softmax + weighted sum + acat build
//   mode-2: out = tanh(acat @ Wc.T + b_comb)

typedef __attribute__((ext_vector_type(8))) short bf16x8;
typedef __attribute__((ext_vector_type(4))) float f32x4;

__device__ __forceinline__ float bf2f(uint16_t u) {
  return __uint_as_float(((uint32_t)u) << 16);
}
__device__ __forceinline__ uint16_t f2bf(float x) {
  uint32_t u = __float_as_uint(x);
  u += 0x7fffu + ((u >> 16) & 1u);   // RNE
  return (uint16_t)(u >> 16);
}
__device__ __forceinline__ uint32_t pk2(float a, float b) {
  return (uint32_t)f2bf(a) | ((uint32_t)f2bf(b) << 16);
}
__device__ __forceinline__ uint4 cvt8(const float* __restrict__ p) {
  const float4 a = *(const float4*)p;
  const float4 b = *(const float4*)(p + 4);
  uint4 r;
  r.x = pk2(a.x, a.y); r.y = pk2(a.z, a.w);
  r.z = pk2(b.x, b.y); r.w = pk2(b.z, b.w);
  return r;
}
// tanh(x) = 1 - 2/(exp(2x)+1)
__device__ __forceinline__ float tanh_fast(float x) {
  const float e = __expf(2.f * x);
  return __builtin_fmaf(-2.f, __builtin_amdgcn_rcpf(e + 1.f), 1.f);
}
__device__ __forceinline__ void load16(const uint16_t* g, uint16_t* l) {
  __builtin_amdgcn_global_load_lds(
      (const __attribute__((address_space(1))) void*)g,
      (__attribute__((address_space(3))) void*)l, 16, 0, 0);
}

// scores = 0 (32768), U[b*2048+j] = b_attn[j] (131072). 128 blocks x 256.
__global__ __launch_bounds__(256)
void init_kernel(float* __restrict__ scores, float* __restrict__ U,
                 const float* __restrict__ ba) {
  const int tid = blockIdx.x * 256 + threadIdx.x;   // [0, 32768)
  scores[tid] = 0.f;
#pragma unroll
  for (int k = 0; k < 4; ++k) {
    const int i = tid * 4 + k;
    U[i] = ba[i & 2047];
  }
}

// one-shot converts: enc (4194304 u4) | Wa right half (262144 u4) | Wc (262144 u4)
__global__ __launch_bounds__(256)
void cvt_all_kernel(const float* __restrict__ enc, const float* __restrict__ Wa,
                    const float* __restrict__ Wc,
                    uint16_t* __restrict__ enc_bf, uint16_t* __restrict__ Wa_bf,
                    uint16_t* __restrict__ Wc_bf) {
  const int stride = gridDim.x * 256;
  for (int idx = blockIdx.x * 256 + threadIdx.x; idx < 4718592; idx += stride) {
    if (idx < 4194304) {
      ((uint4*)enc_bf)[idx] = cvt8(enc + (size_t)idx * 8);
    } else if (idx < 4456448) {
      const int k = idx - 4194304;
      const int j = k >> 7, c8 = k & 127;
      ((uint4*)Wa_bf)[k] = cvt8(Wa + (size_t)j * 2048 + 1024 + c8 * 8);
    } else {
      const int k = idx - 4456448;
      ((uint4*)Wc_bf)[k] = cvt8(Wc + (size_t)k * 8);
    }
  }
}

// split-K U-GEMM: U[b,j] += hidden[b,:]@W_attn[j,:1024].T over K-slice.
// grid (16 n-blocks, 4 k-splits); U prefilled with bias by init_kernel.
__global__ __launch_bounds__(256)
void gemm_u_kernel(const float* __restrict__ A, const float* __restrict__ B32,
                   float* __restrict__ U) {
  __shared__ __align__(16) uint16_t sA[128 * 32];
  __shared__ __align__(16) uint16_t sB[128 * 32];
  const int t = threadIdx.x, lane = t & 63, wave = t >> 6;
  const int wm = wave >> 1, wn = wave & 1;
  const int bn0 = blockIdx.x * 128;
  const int kbase = blockIdx.y * 256;
  const int srow = t >> 2, scol = (t & 3) * 8;
  const int ar0 = min(srow, 63), ar1 = min(64 + srow, 63);
  f32x4 acc[4][4];
#pragma unroll
  for (int i = 0; i < 4; ++i)
#pragma unroll
    for (int j = 0; j < 4; ++j) acc[i][j] = (f32x4){0.f, 0.f, 0.f, 0.f};
  const int mrow = wm * 64 + (lane & 15);
  const int nrow = wn * 64 + (lane & 15);
  const int kq = (lane >> 4) * 8;
  for (int kk = 0; kk < 8; ++kk) {
    const int k0 = kbase + (kk << 5);
    const uint4 va0 = cvt8(A + (size_t)ar0 * 1024 + scol + k0);
    const uint4 va1 = cvt8(A + (size_t)ar1 * 1024 + scol + k0);
    const uint4 vb0 = cvt8(B32 + (size_t)(bn0 + srow) * 2048 + scol + k0);
    const uint4 vb1 = cvt8(B32 + (size_t)(bn0 + 64 + srow) * 2048 + scol + k0);
    __syncthreads();
    *(uint4*)&sA[t * 8] = va0;
    *(uint4*)&sA[2048 + t * 8] = va1;
    *(uint4*)&sB[t * 8] = vb0;
    *(uint4*)&sB[2048 + t * 8] = vb1;
    __syncthreads();
    bf16x8 af[4], bfr[4];
#pragma unroll
    for (int i = 0; i < 4; ++i) af[i] = *(const bf16x8*)&sA[(mrow + i * 16) * 32 + kq];
#pragma unroll
    for (int j = 0; j < 4; ++j) bfr[j] = *(const bf16x8*)&sB[(nrow + j * 16) * 32 + kq];
#pragma unroll
    for (int i = 0; i < 4; ++i)
#pragma unroll
      for (int j = 0; j < 4; ++j)
        acc[i][j] = __builtin_amdgcn_mfma_f32_16x16x32_bf16(af[i], bfr[j], acc[i][j], 0, 0, 0);
  }
  const int colb = lane & 15, rquad = lane >> 4;
#pragma unroll
  for (int i = 0; i < 4; ++i)
#pragma unroll
    for (int r = 0; r < 4; ++r) {
      const int gm = wm * 64 + i * 16 + rquad * 4 + r;
      if (gm < 64) {
#pragma unroll
        for (int j = 0; j < 4; ++j) {
          const int gn = bn0 + wn * 64 + j * 16 + colb;
          atomicAdd(&U[gm * 2048 + gn], acc[i][j][r]);
        }
      }
    }
}

// ---- bf16 GEMM, global_load_lds staging (m97 structure).
// bm0 = blockIdx.x*128 (fast dim -> consecutive blocks share B-tile in L2)
// MODE 1: atomicAdd(scores[gm], sum_n tanh(acc + U[gm&63,gn]) * w2[gn])
// MODE 2: outf[gm*1024+gn] = tanh(acc + bias[gn])
template <int MODE>
__global__ __launch_bounds__(256)
void gemm_bf_kernel(const uint16_t* __restrict__ A, int lda,
                    const uint16_t* __restrict__ Bm, int ldb,
                    int M, int K,
                    float* __restrict__ outf,
                    const float* __restrict__ Ubias,
                    const float* __restrict__ bias) {
  __shared__ __align__(16) uint16_t sAB[2][128 * 32];  // 16 KB; reused as U-tile
  uint16_t* sA = sAB[0];
  uint16_t* sB = sAB[1];
  float* sU = (float*)sAB;

  const int t = threadIdx.x, lane = t & 63, wave = t >> 6;
  const int wm = wave >> 1, wn = wave & 1;
  const int bm0 = blockIdx.x * 128;   // m fast
  const int bn0 = blockIdx.y * 128;   // j slow

  const int srow = t >> 2, scol = (t & 3) * 8;
  const int ar0 = min(bm0 + srow, M - 1);
  const int ar1 = min(bm0 + 64 + srow, M - 1);
  const uint16_t* agp0 = A + (size_t)ar0 * lda + scol;
  const uint16_t* agp1 = A + (size_t)ar1 * lda + scol;
  const uint16_t* bgp0 = Bm + (size_t)(bn0 + srow) * ldb + scol;
  const uint16_t* bgp1 = Bm + (size_t)(bn0 + 64 + srow) * ldb + scol;

  uint16_t* la0 = sA + wave * 512;
  uint16_t* la1 = sA + 2048 + wave * 512;
  uint16_t* lb0 = sB + wave * 512;
  uint16_t* lb1 = sB + 2048 + wave * 512;

  f32x4 acc[4][4];
#pragma unroll
  for (int i = 0; i < 4; ++i)
#pragma unroll
    for (int j = 0; j < 4; ++j) acc[i][j] = (f32x4){0.f, 0.f, 0.f, 0.f};

  const int mrow = wm * 64 + (lane & 15);
  const int nrow = wn * 64 + (lane & 15);
  const int kq = (lane >> 4) * 8;

  const int nsteps = K >> 5;
  for (int kk = 0; kk < nsteps; ++kk) {
    const int k0 = kk << 5;
    load16(agp0 + k0, la0);
    load16(agp1 + k0, la1);
    load16(bgp0 + k0, lb0);
    load16(bgp1 + k0, lb1);
    __syncthreads();

    bf16x8 af[4], bfr[4];
#pragma unroll
    for (int i = 0; i < 4; ++i) af[i] = *(const bf16x8*)&sA[(mrow + i * 16) * 32 + kq];
#pragma unroll
    for (int j = 0; j < 4; ++j) bfr[j] = *(const bf16x8*)&sB[(nrow + j * 16) * 32 + kq];
#pragma unroll
    for (int i = 0; i < 4; ++i)
#pragma unroll
      for (int j = 0; j < 4; ++j)
        acc[i][j] = __builtin_amdgcn_mfma_f32_16x16x32_bf16(af[i], bfr[j], acc[i][j], 0, 0, 0);
    __syncthreads();
  }

  const int colb = lane & 15, rquad = lane >> 4;
  if (MODE == 1) {
    // stage U[0:64, bn0:bn0+128] (f32, 32 KB) into LDS
#pragma unroll
    for (int q = 0; q < 8; ++q) {
      const int idx = t + q * 256;
      const int b = idx >> 5, c4 = idx & 31;
      ((float4*)sU)[idx] = *(const float4*)&Ubias[b * 2048 + bn0 + c4 * 4];
    }
    __syncthreads();
    float w2f[4];
#pragma unroll
    for (int j = 0; j < 4; ++j) w2f[j] = bias[bn0 + wn * 64 + j * 16 + colb];
#pragma unroll
    for (int i = 0; i < 4; ++i) {
#pragma unroll
      for (int r = 0; r < 4; ++r) {
        const int gm = bm0 + wm * 64 + i * 16 + rquad * 4 + r;  // = s*64 + b
        const int bb = gm & 63;
        float p = 0.f;
#pragma unroll
        for (int j = 0; j < 4; ++j) {
          const float u = sU[bb * 128 + wn * 64 + j * 16 + colb];
          p += tanh_fast(acc[i][j][r] + u) * w2f[j];
        }
        p += __shfl_xor(p, 1);
        p += __shfl_xor(p, 2);
        p += __shfl_xor(p, 4);
        p += __shfl_xor(p, 8);
        if (colb == 0) atomicAdd(outf + gm, p);
      }
    }
  } else {
#pragma unroll
    for (int i = 0; i < 4; ++i)
#pragma unroll
      for (int r = 0; r < 4; ++r) {
        const int gm = bm0 + wm * 64 + i * 16 + rquad * 4 + r;
        if (gm < M) {
#pragma unroll
          for (int j = 0; j < 4; ++j) {
            const int gn = bn0 + wn * 64 + j * 16 + colb;
            outf[gm * 1024 + gn] = tanh_fast(acc[i][j][r] + bias[gn]);
          }
        }
      }
  }
}

// fused softmax + applied + acat. grid (64 b, 2 half) x 256 thr.
__global__ __launch_bounds__(256)
void applied_kernel(const uint16_t* __restrict__ encb, const float* __restrict__ dec,
                    const float* __restrict__ scores,
                    float* __restrict__ out_applied, uint16_t* __restrict__ acat) {
  const int b = blockIdx.x, half = blockIdx.y, t = threadIdx.x;
  const int wave = t >> 6, lane = t & 63;
  __shared__ float w[512];
  __shared__ float red[8];
  // softmax over s for this b (each thread owns s=t and s=t+256)
  float v0 = scores[(size_t)t * 64 + b];
  float v1 = scores[(size_t)(t + 256) * 64 + b];
  float mx = fmaxf(v0, v1);
#pragma unroll
  for (int off = 32; off >= 1; off >>= 1) mx = fmaxf(mx, __shfl_xor(mx, off));
  if (lane == 0) red[wave] = mx;
  __syncthreads();
  mx = fmaxf(fmaxf(red[0], red[1]), fmaxf(red[2], red[3]));
  const float e0 = __expf(v0 - mx), e1 = __expf(v1 - mx);
  float sum = e0 + e1;
#pragma unroll
  for (int off = 32; off >= 1; off >>= 1) sum += __shfl_xor(sum, off);
  if (lane == 0) red[4 + wave] = sum;
  __syncthreads();
  sum = (red[4] + red[5]) + (red[6] + red[7]);
  const float inv = 1.f / sum;
  w[t] = e0 * inv;
  w[t + 256] = e1 * inv;
  __syncthreads();
  // applied
  const int h = half * 512 + t * 2;
  const uint32_t* base = (const uint32_t*)encb + (size_t)b * 512 + (h >> 1);
  float a0 = 0.f, a1 = 0.f;
#pragma unroll 8
  for (int s = 0; s < 512; ++s) {
    const uint32_t p = base[(size_t)s * 32768];
    a0 += w[s] * bf2f((uint16_t)(p & 0xffffu));
    a1 += w[s] * bf2f((uint16_t)(p >> 16));
  }
  *(float2*)(out_applied + (size_t)b * 1024 + h) = make_float2(a0, a1);
  *(uint32_t*)(acat + (size_t)b * 2048 + 1024 + h) = pk2(a0, a1);
  *(uint32_t*)(acat + (size_t)b * 2048 + h) =
      pk2(dec[(size_t)b * 1024 + h], dec[(size_t)b * 1024 + h + 1]);
}

extern "C" void kernel_launch(void* const* d_in, const int* in_sizes, int n_in,
                              void* d_out, int out_size, void* d_ws, size_t ws_size,
                              hipStream_t stream) {
  const float* hidden  = (const float*)d_in[0];
  const float* dec     = (const float*)d_in[1];
  const float* enc     = (const float*)d_in[2];
  const float* W_attn  = (const float*)d_in[3];
  const float* b_attn  = (const float*)d_in[4];
  const float* W_attn2 = (const float*)d_in[5];
  const float* W_comb  = (const float*)d_in[7];
  const float* b_comb  = (const float*)d_in[8];
  float* outp = (float*)d_out;                 // [out 65536 | applied 65536] f32

  char* ws = (char*)d_ws;
  float*    scores = (float*)(ws + 0);             // 128 KB
  float*    U      = (float*)(ws + 131072);        // 512 KB
  uint16_t* acat   = (uint16_t*)(ws + 655360);     // 256 KB
  uint16_t* enc_bf = (uint16_t*)(ws + 1048576);    // 64 MB
  uint16_t* Wa_bf  = (uint16_t*)(ws + 68157440);   // 4 MB  [2048,1024]
  uint16_t* Wc_bf  = (uint16_t*)(ws + 72351744);   // 4 MB  [1024,2048]

  init_kernel<<<128, 256, 0, stream>>>(scores, U, b_attn);
  cvt_all_kernel<<<4608, 256, 0, stream>>>(enc, W_attn, W_comb, enc_bf, Wa_bf, Wc_bf);
  gemm_u_kernel<<<dim3(16, 4), 256, 0, stream>>>(hidden, W_attn, U);
  gemm_bf_kernel<1><<<dim3(256, 16), 256, 0, stream>>>(
      enc_bf, 1024, Wa_bf, 1024, 32768, 1024, scores, U, W_attn2);
  applied_kernel<<<dim3(64, 2), 256, 0, stream>>>(enc_bf, dec, scores, outp + 65536, acat);
  gemm_bf_kernel<2><<<dim3(1, 8), 256, 0, stream>>>(
      acat, 2048, Wc_bf, 2048, 64, 2048, outp, nullptr, b_comb);
}